// Round 1
// baseline (450.926 us; speedup 1.0000x reference)
//
#include <hip/hip_runtime.h>
#include <hip/hip_bf16.h>

#define STEP_F (1.0f/9.0f)

// ---------------- conv + bias + relu + optional BN affine ----------------
__global__ __launch_bounds__(256) void conv_k(
    const float* __restrict__ x, const float* __restrict__ w,
    const float* __restrict__ bias,
    const float* __restrict__ g, const float* __restrict__ be,
    const float* __restrict__ mn, const float* __restrict__ vr,
    float* __restrict__ y,
    int Bn, int Ci, int Co, int IH, int IW, int OH, int OW, int hasBN)
{
    int total = Bn * Co * OH * OW;
    int idx = blockIdx.x * blockDim.x + threadIdx.x;
    if (idx >= total) return;
    int ow = idx % OW;
    int t  = idx / OW;
    int oh = t % OH; t /= OH;
    int co = t % Co;
    int b  = t / Co;

    const float* xb = x + (size_t)b * Ci * IH * IW;
    const float* wc = w + (size_t)co * Ci * 9;
    float acc = bias[co];
    int ih0 = oh * 2, iw0 = ow * 2;
    for (int ci = 0; ci < Ci; ++ci) {
        const float* xp = xb + (size_t)ci * IH * IW + (size_t)ih0 * IW + iw0;
        const float* wp = wc + ci * 9;
        acc += xp[0]        * wp[0] + xp[1]        * wp[1] + xp[2]        * wp[2]
             + xp[IW]       * wp[3] + xp[IW+1]     * wp[4] + xp[IW+2]     * wp[5]
             + xp[2*IW]     * wp[6] + xp[2*IW+1]   * wp[7] + xp[2*IW+2]   * wp[8];
    }
    acc = fmaxf(acc, 0.0f);
    if (hasBN) {
        float s = g[co] / sqrtf(vr[co] + 1e-5f);
        acc = (acc - mn[co]) * s + be[co];
    }
    y[idx] = acc;
}

// ---------------- global mean over 7x7 ----------------
__global__ __launch_bounds__(256) void mean_k(const float* __restrict__ y5,
                                              float* __restrict__ feat)
{
    int idx = blockIdx.x * blockDim.x + threadIdx.x;
    if (idx >= 64 * 128) return;
    const float* p = y5 + (size_t)idx * 49;
    float s = 0.0f;
    #pragma unroll
    for (int i = 0; i < 49; ++i) s += p[i];
    feat[idx] = s * (1.0f / 49.0f);
}

// ---------------- fully connected (out = in @ W^T + b, optional relu) ----------------
__global__ __launch_bounds__(256) void fc_k(const float* __restrict__ in,
                                            const float* __restrict__ w,
                                            const float* __restrict__ bias,
                                            float* __restrict__ out,
                                            int Bn, int K, int O, int doRelu)
{
    int idx = blockIdx.x * blockDim.x + threadIdx.x;
    if (idx >= Bn * O) return;
    int o = idx % O, b = idx / O;
    const float* ip = in + (size_t)b * K;
    const float* wp = w + (size_t)o * K;
    float s = bias[o];
    for (int k = 0; k < K; ++k) s += ip[k] * wp[k];
    out[idx] = doRelu ? fmaxf(s, 0.0f) : s;
}

// ---------------- spline coefficients: natural cubic, N=10 knots ----------------
// One thread per (b,e,c) row, idx = b*6 + e*3 + c, 384 rows total.
// Solves tridiag(1,4,1) * M[1..8] = 6/h^2 * (yt[i] - 2 yt[i+1] + yt[i+2]) via Thomas.
__global__ __launch_bounds__(256) void coeffs_k(const float* __restrict__ ys,
                                                float* __restrict__ coef)
{
    int idx = blockIdx.x * blockDim.x + threadIdx.x;
    if (idx >= 64 * 2 * 3) return;
    const float h = STEP_F;
    float yt[10];
    const float* yp = ys + (size_t)idx * 10;
    #pragma unroll
    for (int n = 0; n < 10; ++n) yt[n] = yp[n] + (float)n * h;

    float r[8];
    const float k6h2 = 6.0f / (h * h);
    #pragma unroll
    for (int i = 0; i < 8; ++i) r[i] = k6h2 * (yt[i] - 2.0f * yt[i+1] + yt[i+2]);

    // Thomas on tridiag(1,4,1), n=8
    float cp[8], dp[8];
    cp[0] = 0.25f; dp[0] = r[0] * 0.25f;
    #pragma unroll
    for (int i = 1; i < 8; ++i) {
        float m = 4.0f - cp[i-1];
        cp[i] = 1.0f / m;
        dp[i] = (r[i] - dp[i-1]) / m;
    }
    float M[10];
    M[0] = 0.0f; M[9] = 0.0f;
    M[8] = dp[7];
    #pragma unroll
    for (int i = 6; i >= 0; --i) M[i+1] = dp[i] - cp[i] * M[i+2];

    float* cf = coef + (size_t)idx * 36;
    #pragma unroll
    for (int i = 0; i < 9; ++i) {
        cf[i]      = (M[i+1] - M[i]) / (6.0f * h);
        cf[9 + i]  = M[i] * 0.5f;
        cf[18 + i] = (yt[i+1] - yt[i]) / h - (M[i+1] + 2.0f * M[i]) * (h / 6.0f);
        cf[27 + i] = yt[i];
    }
}

// ---------------- apply spline to batch pixels ----------------
// blockIdx.y = b*3+ch  (192 rows), blockIdx.x = pixel chunk. Each thread: one float4.
__global__ __launch_bounds__(256) void apply_k(const float* __restrict__ batch,
                                               const float* __restrict__ coef,
                                               float* __restrict__ out)
{
    __shared__ float cf[72];
    int bc = blockIdx.y;
    int b = bc / 3, ch = bc % 3;
    if (threadIdx.x < 72) {
        int e = threadIdx.x / 36;
        int j = threadIdx.x % 36;
        cf[threadIdx.x] = coef[((size_t)(b * 6 + e * 3 + ch)) * 36 + j];
    }
    __syncthreads();

    const int P = 65536;
    size_t base = ((size_t)b * 3 + ch) * P;
    int p0 = (blockIdx.x * blockDim.x + threadIdx.x) * 4;

    float4 xv = *(const float4*)(batch + base + p0);
    float r0[4], r1[4];
    float xs[4] = {xv.x, xv.y, xv.z, xv.w};
    #pragma unroll
    for (int k = 0; k < 4; ++k) {
        float x = xs[k];
        int xi = (int)floorf(x / STEP_F);
        xi = xi < 0 ? 0 : (xi > 8 ? 8 : xi);
        float xf = x - (float)xi * STEP_F;
        {
            const float* c = cf;
            r0[k] = ((c[xi] * xf + c[9 + xi]) * xf + c[18 + xi]) * xf + c[27 + xi];
        }
        {
            const float* c = cf + 36;
            r1[k] = ((c[xi] * xf + c[9 + xi]) * xf + c[18 + xi]) * xf + c[27 + xi];
        }
    }
    float4 o0 = {r0[0], r0[1], r0[2], r0[3]};
    float4 o1 = {r1[0], r1[1], r1[2], r1[3]};
    size_t off0 = (((size_t)0 * 64 + b) * 3 + ch) * P + p0;
    size_t off1 = (((size_t)1 * 64 + b) * 3 + ch) * P + p0;
    *(float4*)(out + off0) = o0;
    *(float4*)(out + off1) = o1;
}

// ---------------- splines LUT output: (E,B,3,255) ----------------
__global__ __launch_bounds__(256) void splines_k(const float* __restrict__ coef,
                                                 float* __restrict__ out)
{
    int idx = blockIdx.x * blockDim.x + threadIdx.x;
    const int TOT = 2 * 64 * 3 * 255;
    if (idx >= TOT) return;
    int v = idx % 255; int t = idx / 255;
    int ch = t % 3; t /= 3;
    int b = t % 64; int e = t / 64;
    float val = (float)v * (1.0f / 255.0f);
    int vi = (int)floorf(val / STEP_F);
    vi = vi < 0 ? 0 : (vi > 8 ? 8 : vi);
    float vf = val - (float)vi * STEP_F;
    const float* c = coef + ((size_t)(b * 6 + e * 3 + ch)) * 36;
    out[idx] = ((c[vi] * vf + c[9 + vi]) * vf + c[18 + vi]) * vf + c[27 + vi];
}

extern "C" void kernel_launch(void* const* d_in, const int* in_sizes, int n_in,
                              void* d_out, int out_size, void* d_ws, size_t ws_size,
                              hipStream_t stream) {
    const float* batch = (const float*)d_in[0];
    const float* w1 = (const float*)d_in[1];  const float* b1 = (const float*)d_in[2];
    const float* w2 = (const float*)d_in[3];  const float* b2 = (const float*)d_in[4];
    const float* w3 = (const float*)d_in[5];  const float* b3 = (const float*)d_in[6];
    const float* w4 = (const float*)d_in[7];  const float* b4 = (const float*)d_in[8];
    const float* w5 = (const float*)d_in[9];  const float* b5 = (const float*)d_in[10];
    const float* bn2g = (const float*)d_in[11]; const float* bn2b = (const float*)d_in[12];
    const float* bn2m = (const float*)d_in[13]; const float* bn2v = (const float*)d_in[14];
    const float* bn3g = (const float*)d_in[15]; const float* bn3b = (const float*)d_in[16];
    const float* bn3m = (const float*)d_in[17]; const float* bn3v = (const float*)d_in[18];
    const float* bn4g = (const float*)d_in[19]; const float* bn4b = (const float*)d_in[20];
    const float* bn4m = (const float*)d_in[21]; const float* bn4v = (const float*)d_in[22];
    const float* bn5g = (const float*)d_in[23]; const float* bn5b = (const float*)d_in[24];
    const float* bn5m = (const float*)d_in[25]; const float* bn5v = (const float*)d_in[26];
    const float* l1w = (const float*)d_in[27]; const float* l1b = (const float*)d_in[28];
    const float* l2w = (const float*)d_in[29]; const float* l2b = (const float*)d_in[30];

    float* outp = (float*)d_out;
    // Conv intermediates live in the (later fully overwritten) out region.
    float* y1 = outp;                 // 64*8*127*127   = 8,258,048
    float* y2 = y1 + 8258048;         // 64*16*63*63    = 4,064,256
    float* y3 = y2 + 4064256;         // 64*32*31*31    = 1,968,128
    float* y4 = y3 + 1968128;         // 64*64*15*15    =   921,600
    float* y5 = y4 + 921600;          // 64*128*7*7     =   401,408
    // total 15,613,440 < 25,165,824 (the "out" tensor size) — safe.

    float* ws   = (float*)d_ws;
    float* feat = ws;            // 8192
    float* hh   = feat + 8192;   // 8192
    float* ysb  = hh + 8192;     // 3840
    float* coef = ysb + 3840;    // 13824

    const int TPB = 256;
    // conv1: 3->8, 256->127, relu only
    {
        int total = 64 * 8 * 127 * 127;
        conv_k<<<(total + TPB - 1) / TPB, TPB, 0, stream>>>(
            batch, w1, b1, nullptr, nullptr, nullptr, nullptr, y1,
            64, 3, 8, 256, 256, 127, 127, 0);
    }
    // conv2: 8->16, 127->63, relu+bn
    {
        int total = 64 * 16 * 63 * 63;
        conv_k<<<(total + TPB - 1) / TPB, TPB, 0, stream>>>(
            y1, w2, b2, bn2g, bn2b, bn2m, bn2v, y2,
            64, 8, 16, 127, 127, 63, 63, 1);
    }
    // conv3: 16->32, 63->31
    {
        int total = 64 * 32 * 31 * 31;
        conv_k<<<(total + TPB - 1) / TPB, TPB, 0, stream>>>(
            y2, w3, b3, bn3g, bn3b, bn3m, bn3v, y3,
            64, 16, 32, 63, 63, 31, 31, 1);
    }
    // conv4: 32->64, 31->15
    {
        int total = 64 * 64 * 15 * 15;
        conv_k<<<(total + TPB - 1) / TPB, TPB, 0, stream>>>(
            y3, w4, b4, bn4g, bn4b, bn4m, bn4v, y4,
            64, 32, 64, 31, 31, 15, 15, 1);
    }
    // conv5: 64->128, 15->7
    {
        int total = 64 * 128 * 7 * 7;
        conv_k<<<(total + TPB - 1) / TPB, TPB, 0, stream>>>(
            y4, w5, b5, bn5g, bn5b, bn5m, bn5v, y5,
            64, 64, 128, 15, 15, 7, 7, 1);
    }
    // mean pool
    mean_k<<<(64 * 128 + TPB - 1) / TPB, TPB, 0, stream>>>(y5, feat);
    // fc1: 128->128 relu
    fc_k<<<(64 * 128 + TPB - 1) / TPB, TPB, 0, stream>>>(feat, l1w, l1b, hh, 64, 128, 128, 1);
    // fc2: 128->60
    fc_k<<<(64 * 60 + TPB - 1) / TPB, TPB, 0, stream>>>(hh, l2w, l2b, ysb, 64, 128, 60, 0);
    // spline coefficients
    coeffs_k<<<2, TPB, 0, stream>>>(ysb, coef);
    // apply to batch: grid (64 chunks, 192 (b,ch) rows)
    {
        dim3 grid(64, 192);
        apply_k<<<grid, TPB, 0, stream>>>(batch, coef, outp);
    }
    // splines LUT
    {
        int tot = 2 * 64 * 3 * 255;
        splines_k<<<(tot + TPB - 1) / TPB, TPB, 0, stream>>>(coef, outp + 25165824);
    }
}

// Round 2
// 194.257 us; speedup vs baseline: 2.3213x; 2.3213x over previous
//
#include <hip/hip_runtime.h>
#include <hip/hip_bf16.h>

#define STEP_F (1.0f/9.0f)

// ---------------- conv1: 3->8, 256x256 -> 127x127, stride 2, relu ----------------
// thread = (b, oh, ow-group-of-4); computes all 8 co. Weights wave-uniform -> s_load.
__global__ __launch_bounds__(256) void conv1_k(const float* __restrict__ x,
                                               const float* __restrict__ w,
                                               const float* __restrict__ bias,
                                               float* __restrict__ y)
{
    int idx = blockIdx.x * 256 + threadIdx.x;
    int owg = idx & 31;
    int t1  = idx >> 5;
    int oh  = t1 % 127;
    int b   = t1 / 127;
    int iw0 = owg * 8;
    int ih0 = oh * 2;
    const float* xb = x + (size_t)b * 3 * 65536;

    float acc[8][4];
    #pragma unroll
    for (int c = 0; c < 8; ++c)
        #pragma unroll
        for (int t = 0; t < 4; ++t) acc[c][t] = 0.0f;

    for (int ci = 0; ci < 3; ++ci) {
        float r[3][10];
        #pragma unroll
        for (int kh = 0; kh < 3; ++kh) {
            const float* row = xb + ci * 65536 + (ih0 + kh) * 256;
            #pragma unroll
            for (int t = 0; t < 5; ++t) {
                int c = iw0 + 2 * t; if (c > 254) c = 254;   // only affects masked outputs
                float2 v = *(const float2*)(row + c);
                r[kh][2*t] = v.x; r[kh][2*t+1] = v.y;
            }
        }
        #pragma unroll
        for (int co = 0; co < 8; ++co) {
            float wr[9];
            #pragma unroll
            for (int k = 0; k < 9; ++k) wr[k] = w[(co * 3 + ci) * 9 + k];  // uniform -> s_load
            #pragma unroll
            for (int t = 0; t < 4; ++t) {
                float a = acc[co][t];
                #pragma unroll
                for (int kh = 0; kh < 3; ++kh)
                    a = fmaf(r[kh][2*t+0], wr[kh*3+0],
                        fmaf(r[kh][2*t+1], wr[kh*3+1],
                        fmaf(r[kh][2*t+2], wr[kh*3+2], a)));
                acc[co][t] = a;
            }
        }
    }
    int ow0 = owg * 4;
    #pragma unroll
    for (int co = 0; co < 8; ++co) {
        float bs = bias[co];
        #pragma unroll
        for (int t = 0; t < 4; ++t) {
            int ow = ow0 + t;
            if (ow < 127)
                y[(((size_t)b * 8 + co) * 127 + oh) * 127 + ow] = fmaxf(acc[co][t] + bs, 0.0f);
        }
    }
}

// ---------------- convs 2-5: LDS-tiled, wave-uniform co-group, bias+relu+BN ----------------
// Block: (b, oh-tile, 16-co slice). Lanes: ow (OWS slots) x r0 (NR rows), RPT rows/thread.
template<int CI, int CO, int IH, int IW, int OH, int OW, int RPT>
__global__ __launch_bounds__(256) void convt_k(
    const float* __restrict__ x, const float* __restrict__ w,
    const float* __restrict__ bias,
    const float* __restrict__ g, const float* __restrict__ be,
    const float* __restrict__ mn, const float* __restrict__ vr,
    float* __restrict__ y)
{
    constexpr int RS  = IW + 1;                 // pow2 row stride
    constexpr int OWS = RS / 2;                 // lane slots per row
    constexpr int NR  = 64 / OWS;
    constexpr int OHT = NR * RPT;
    constexpr int TIH = (2*OHT+1) < IH ? (2*OHT+1) : IH;
    constexpr int STR = 256 / RS;

    __shared__ float lds[CI * TIH * RS + 80];   // +pad: masked-lane reads run past end

    const int b       = blockIdx.x;
    const int oh_base = blockIdx.y * OHT;
    const int co_base = blockIdx.z * 16;

    // stage input tile (coalesced; rows beyond IH skipped)
    {
        const int col = threadIdx.x & (RS - 1);
        const int rp0 = threadIdx.x / RS;
        const int ih0 = oh_base * 2;
        const int tihc = (TIH < IH - ih0) ? TIH : (IH - ih0);
        if (col < IW) {
            for (int ci = 0; ci < CI; ++ci) {
                const float* gp = x + (((size_t)b * CI + ci) * IH + ih0) * IW + col;
                float* lp = lds + (ci * TIH) * RS + col;
                for (int rr = rp0; rr < tihc; rr += STR)
                    lp[rr * RS] = gp[(size_t)rr * IW];
            }
        }
    }
    __syncthreads();

    const int lane = threadIdx.x & 63;
    const int wv   = __builtin_amdgcn_readfirstlane(threadIdx.x >> 6);
    const int co0  = co_base + wv * 4;
    const int ow   = lane & (OWS - 1);
    const int r0   = lane / OWS;

    float acc[4][RPT];
    #pragma unroll
    for (int c = 0; c < 4; ++c)
        #pragma unroll
        for (int j = 0; j < RPT; ++j) acc[c][j] = 0.0f;

    for (int ci = 0; ci < CI; ++ci) {
        float wr[4][9];
        #pragma unroll
        for (int c = 0; c < 4; ++c)
            #pragma unroll
            for (int k = 0; k < 9; ++k)
                wr[c][k] = w[(((size_t)(co0 + c)) * CI + ci) * 9 + k];  // uniform -> s_load
        const float* lci = lds + ci * TIH * RS;
        #pragma unroll
        for (int j = 0; j < RPT; ++j) {
            #pragma unroll
            for (int kh = 0; kh < 3; ++kh) {
                const float* lr = lci + (2 * (r0 * RPT + j) + kh) * RS + 2 * ow;
                float x0 = lr[0], x1 = lr[1], x2 = lr[2];
                #pragma unroll
                for (int c = 0; c < 4; ++c)
                    acc[c][j] = fmaf(x0, wr[c][kh*3+0],
                                fmaf(x1, wr[c][kh*3+1],
                                fmaf(x2, wr[c][kh*3+2], acc[c][j])));
            }
        }
    }

    #pragma unroll
    for (int c = 0; c < 4; ++c) {
        const int co = co0 + c;
        const float bs = bias[co];
        const float s  = g[co] / sqrtf(vr[co] + 1e-5f);
        const float sh = be[co] - mn[co] * s;
        if (ow < OW) {
            #pragma unroll
            for (int j = 0; j < RPT; ++j) {
                int oh = oh_base + r0 * RPT + j;
                if (oh < OH)
                    y[(((size_t)b * CO + co) * OH + oh) * OW + ow] =
                        fmaxf(acc[c][j] + bs, 0.0f) * s + sh;
            }
        }
    }
}

// ---------------- global mean over 7x7 ----------------
__global__ __launch_bounds__(256) void mean_k(const float* __restrict__ y5,
                                              float* __restrict__ feat)
{
    int idx = blockIdx.x * blockDim.x + threadIdx.x;
    if (idx >= 64 * 128) return;
    const float* p = y5 + (size_t)idx * 49;
    float s = 0.0f;
    #pragma unroll
    for (int i = 0; i < 49; ++i) s += p[i];
    feat[idx] = s * (1.0f / 49.0f);
}

// ---------------- fully connected ----------------
__global__ __launch_bounds__(256) void fc_k(const float* __restrict__ in,
                                            const float* __restrict__ w,
                                            const float* __restrict__ bias,
                                            float* __restrict__ out,
                                            int Bn, int K, int O, int doRelu)
{
    int idx = blockIdx.x * blockDim.x + threadIdx.x;
    if (idx >= Bn * O) return;
    int o = idx % O, b = idx / O;
    const float* ip = in + (size_t)b * K;
    const float* wp = w + (size_t)o * K;
    float s = bias[o];
    for (int k = 0; k < K; ++k) s += ip[k] * wp[k];
    out[idx] = doRelu ? fmaxf(s, 0.0f) : s;
}

// ---------------- spline coefficients (Thomas solve of tridiag(1,4,1)) ----------------
__global__ __launch_bounds__(256) void coeffs_k(const float* __restrict__ ys,
                                                float* __restrict__ coef)
{
    int idx = blockIdx.x * blockDim.x + threadIdx.x;
    if (idx >= 64 * 2 * 3) return;
    const float h = STEP_F;
    float yt[10];
    const float* yp = ys + (size_t)idx * 10;
    #pragma unroll
    for (int n = 0; n < 10; ++n) yt[n] = yp[n] + (float)n * h;

    float r[8];
    const float k6h2 = 6.0f / (h * h);
    #pragma unroll
    for (int i = 0; i < 8; ++i) r[i] = k6h2 * (yt[i] - 2.0f * yt[i+1] + yt[i+2]);

    float cp[8], dp[8];
    cp[0] = 0.25f; dp[0] = r[0] * 0.25f;
    #pragma unroll
    for (int i = 1; i < 8; ++i) {
        float m = 4.0f - cp[i-1];
        cp[i] = 1.0f / m;
        dp[i] = (r[i] - dp[i-1]) / m;
    }
    float M[10];
    M[0] = 0.0f; M[9] = 0.0f;
    M[8] = dp[7];
    #pragma unroll
    for (int i = 6; i >= 0; --i) M[i+1] = dp[i] - cp[i] * M[i+2];

    float* cf = coef + (size_t)idx * 36;
    #pragma unroll
    for (int i = 0; i < 9; ++i) {
        cf[i]      = (M[i+1] - M[i]) / (6.0f * h);
        cf[9 + i]  = M[i] * 0.5f;
        cf[18 + i] = (yt[i+1] - yt[i]) / h - (M[i+1] + 2.0f * M[i]) * (h / 6.0f);
        cf[27 + i] = yt[i];
    }
}

// ---------------- apply spline to batch pixels ----------------
__global__ __launch_bounds__(256) void apply_k(const float* __restrict__ batch,
                                               const float* __restrict__ coef,
                                               float* __restrict__ out)
{
    __shared__ float cf[72];
    int bc = blockIdx.y;
    int b = bc / 3, ch = bc % 3;
    if (threadIdx.x < 72) {
        int e = threadIdx.x / 36;
        int j = threadIdx.x % 36;
        cf[threadIdx.x] = coef[((size_t)(b * 6 + e * 3 + ch)) * 36 + j];
    }
    __syncthreads();

    const int P = 65536;
    size_t base = ((size_t)b * 3 + ch) * P;
    int p0 = (blockIdx.x * blockDim.x + threadIdx.x) * 4;

    float4 xv = *(const float4*)(batch + base + p0);
    float r0[4], r1[4];
    float xs[4] = {xv.x, xv.y, xv.z, xv.w};
    #pragma unroll
    for (int k = 0; k < 4; ++k) {
        float x = xs[k];
        int xi = (int)floorf(x / STEP_F);
        xi = xi < 0 ? 0 : (xi > 8 ? 8 : xi);
        float xf = x - (float)xi * STEP_F;
        {
            const float* c = cf;
            r0[k] = ((c[xi] * xf + c[9 + xi]) * xf + c[18 + xi]) * xf + c[27 + xi];
        }
        {
            const float* c = cf + 36;
            r1[k] = ((c[xi] * xf + c[9 + xi]) * xf + c[18 + xi]) * xf + c[27 + xi];
        }
    }
    float4 o0 = {r0[0], r0[1], r0[2], r0[3]};
    float4 o1 = {r1[0], r1[1], r1[2], r1[3]};
    size_t off0 = (((size_t)0 * 64 + b) * 3 + ch) * P + p0;
    size_t off1 = (((size_t)1 * 64 + b) * 3 + ch) * P + p0;
    *(float4*)(out + off0) = o0;
    *(float4*)(out + off1) = o1;
}

// ---------------- splines LUT output: (E,B,3,255) ----------------
__global__ __launch_bounds__(256) void splines_k(const float* __restrict__ coef,
                                                 float* __restrict__ out)
{
    int idx = blockIdx.x * blockDim.x + threadIdx.x;
    const int TOT = 2 * 64 * 3 * 255;
    if (idx >= TOT) return;
    int v = idx % 255; int t = idx / 255;
    int ch = t % 3; t /= 3;
    int b = t % 64; int e = t / 64;
    float val = (float)v * (1.0f / 255.0f);
    int vi = (int)floorf(val / STEP_F);
    vi = vi < 0 ? 0 : (vi > 8 ? 8 : vi);
    float vf = val - (float)vi * STEP_F;
    const float* c = coef + ((size_t)(b * 6 + e * 3 + ch)) * 36;
    out[idx] = ((c[vi] * vf + c[9 + vi]) * vf + c[18 + vi]) * vf + c[27 + vi];
}

extern "C" void kernel_launch(void* const* d_in, const int* in_sizes, int n_in,
                              void* d_out, int out_size, void* d_ws, size_t ws_size,
                              hipStream_t stream) {
    const float* batch = (const float*)d_in[0];
    const float* w1 = (const float*)d_in[1];  const float* b1 = (const float*)d_in[2];
    const float* w2 = (const float*)d_in[3];  const float* b2 = (const float*)d_in[4];
    const float* w3 = (const float*)d_in[5];  const float* b3 = (const float*)d_in[6];
    const float* w4 = (const float*)d_in[7];  const float* b4 = (const float*)d_in[8];
    const float* w5 = (const float*)d_in[9];  const float* b5 = (const float*)d_in[10];
    const float* bn2g = (const float*)d_in[11]; const float* bn2b = (const float*)d_in[12];
    const float* bn2m = (const float*)d_in[13]; const float* bn2v = (const float*)d_in[14];
    const float* bn3g = (const float*)d_in[15]; const float* bn3b = (const float*)d_in[16];
    const float* bn3m = (const float*)d_in[17]; const float* bn3v = (const float*)d_in[18];
    const float* bn4g = (const float*)d_in[19]; const float* bn4b = (const float*)d_in[20];
    const float* bn4m = (const float*)d_in[21]; const float* bn4v = (const float*)d_in[22];
    const float* bn5g = (const float*)d_in[23]; const float* bn5b = (const float*)d_in[24];
    const float* bn5m = (const float*)d_in[25]; const float* bn5v = (const float*)d_in[26];
    const float* l1w = (const float*)d_in[27]; const float* l1b = (const float*)d_in[28];
    const float* l2w = (const float*)d_in[29]; const float* l2b = (const float*)d_in[30];

    float* outp = (float*)d_out;
    float* y1 = outp;                 // 64*8*127*127   = 8,258,048
    float* y2 = y1 + 8258048;         // 64*16*63*63    = 4,064,256
    float* y3 = y2 + 4064256;         // 64*32*31*31    = 1,968,128
    float* y4 = y3 + 1968128;         // 64*64*15*15    =   921,600
    float* y5 = y4 + 921600;          // 64*128*7*7     =   401,408

    float* ws   = (float*)d_ws;
    float* feat = ws;            // 8192
    float* hh   = feat + 8192;   // 8192
    float* ysb  = hh + 8192;     // 3840
    float* coef = ysb + 3840;    // 13824

    const int TPB = 256;
    // conv1: 64*127*32 threads = 1016 blocks exactly
    conv1_k<<<1016, TPB, 0, stream>>>(batch, w1, b1, y1);
    // conv2: 8->16, 127->63
    convt_k<8, 16, 127, 127, 63, 63, 4><<<dim3(64, 16, 1), TPB, 0, stream>>>(
        y1, w2, b2, bn2g, bn2b, bn2m, bn2v, y2);
    // conv3: 16->32, 63->31
    convt_k<16, 32, 63, 63, 31, 31, 2><<<dim3(64, 8, 2), TPB, 0, stream>>>(
        y2, w3, b3, bn3g, bn3b, bn3m, bn3v, y3);
    // conv4: 32->64, 31->15
    convt_k<32, 64, 31, 31, 15, 15, 1><<<dim3(64, 4, 4), TPB, 0, stream>>>(
        y3, w4, b4, bn4g, bn4b, bn4m, bn4v, y4);
    // conv5: 64->128, 15->7
    convt_k<64, 128, 15, 15, 7, 7, 1><<<dim3(64, 1, 8), TPB, 0, stream>>>(
        y4, w5, b5, bn5g, bn5b, bn5m, bn5v, y5);
    // mean pool
    mean_k<<<(64 * 128 + TPB - 1) / TPB, TPB, 0, stream>>>(y5, feat);
    // fc1: 128->128 relu
    fc_k<<<(64 * 128 + TPB - 1) / TPB, TPB, 0, stream>>>(feat, l1w, l1b, hh, 64, 128, 128, 1);
    // fc2: 128->60
    fc_k<<<(64 * 60 + TPB - 1) / TPB, TPB, 0, stream>>>(hh, l2w, l2b, ysb, 64, 128, 60, 0);
    // spline coefficients
    coeffs_k<<<2, TPB, 0, stream>>>(ysb, coef);
    // apply to batch
    {
        dim3 grid(64, 192);
        apply_k<<<grid, TPB, 0, stream>>>(batch, coef, outp);
    }
    // splines LUT
    {
        int tot = 2 * 64 * 3 * 255;
        splines_k<<<(tot + TPB - 1) / TPB, TPB, 0, stream>>>(coef, outp + 25165824);
    }
}